// Round 2
// baseline (267.521 us; speedup 1.0000x reference)
//
#include <hip/hip_runtime.h>
#include <hip/hip_bf16.h>
#include <math.h>

#define BB 512
#define SS 50
#define EE 128
#define HH 8
#define RR 32
#define NC 5
#define NSEQ 20000
#define NBS (BB*SS)   // 25600

__device__ __forceinline__ void fma4(float4& a, float s, const float4& w) {
    a.x = fmaf(s, w.x, a.x);
    a.y = fmaf(s, w.y, a.y);
    a.z = fmaf(s, w.z, a.z);
    a.w = fmaf(s, w.w, a.w);
}

__device__ __forceinline__ float dot4(const float4& a, const float4& b) {
    return a.x*b.x + a.y*b.y + a.z*b.z + a.w*b.w;
}

// -------------------- sort kernels: counting sort of bs-indices by seq value --------------------
__global__ __launch_bounds__(256) void hist_kernel(const int* __restrict__ seq,
                                                   int* __restrict__ hist) {
    int i = blockIdx.x * 256 + threadIdx.x;
    if (i < NBS) atomicAdd(&hist[seq[i]], 1);
}

// single block, 1024 threads: exclusive scan of hist[NSEQ] in place
__global__ __launch_bounds__(1024) void scan_kernel(int* __restrict__ hist) {
    const int t = threadIdx.x;
    const int CH = 20;                      // 1024*20 = 20480 >= 20000
    const int base = t * CH;
    int loc[CH];
    int s = 0;
    #pragma unroll
    for (int i = 0; i < CH; ++i) {
        int idx = base + i;
        int v = (idx < NSEQ) ? hist[idx] : 0;
        loc[i] = s; s += v;
    }
    // block exclusive scan of per-thread sums
    const int lane = t & 63, w = t >> 6;    // 16 waves
    int incl = s;
    #pragma unroll
    for (int off = 1; off < 64; off <<= 1) {
        int n = __shfl_up(incl, off);
        if (lane >= off) incl += n;
    }
    __shared__ int wsum[16];
    if (lane == 63) wsum[w] = incl;
    __syncthreads();
    if (t == 0) {
        int acc = 0;
        #pragma unroll
        for (int k = 0; k < 16; ++k) { int v = wsum[k]; wsum[k] = acc; acc += v; }
    }
    __syncthreads();
    const int excl = incl - s + wsum[w];
    #pragma unroll
    for (int i = 0; i < CH; ++i) {
        int idx = base + i;
        if (idx < NSEQ) hist[idx] = excl + loc[i];
    }
}

__global__ __launch_bounds__(256) void scatter_kernel(const int* __restrict__ seq,
                                                      int* __restrict__ hist,
                                                      int* __restrict__ perm) {
    int i = blockIdx.x * 256 + threadIdx.x;
    if (i < NBS) {
        int pos = atomicAdd(&hist[seq[i]], 1);
        perm[pos] = i;
    }
}

// -------------------- Kernel 1: attention (blocks 0..BB-1)  ||  item-profile (rest) --------------------
union SMemU {
    struct {
        float ne[SS][EE];
        float vbuf[SS][EE];
        float ue[EE];
        float qs[EE];
        float attn[HH][SS];
        float maskadd[SS];
    } a;
    struct {
        float ier[EE];
    } r;
};

__global__ __launch_bounds__(256) void attn_item_kernel(
    const int* __restrict__ user, const int* __restrict__ item,
    const int* __restrict__ neighbor, const int* __restrict__ seq,
    const float* __restrict__ uet, const float* __restrict__ iet,
    const float* __restrict__ ui_lcu,
    const float* __restrict__ wq, const float* __restrict__ bq,
    const float* __restrict__ wk, const float* __restrict__ bk,
    const float* __restrict__ wv, const float* __restrict__ bv,
    const float* __restrict__ wo, const float* __restrict__ bo,
    const int* __restrict__ perm,
    float* __restrict__ ws_ne2, float* __restrict__ ws_ip)
{
    __shared__ SMemU sm;
    const int t = threadIdx.x;

    if (blockIdx.x >= BB) {
        // ---------------- item-profile path (BW-bound, sorted by seq) ----------------
        const int bs = perm[blockIdx.x - BB];
        const int b  = bs / SS;
        const int j  = seq[bs];
        if (t < EE) sm.r.ier[t] = iet[(size_t)item[b]*EE + t];
        __syncthreads();

        const int r = t >> 3, l = t & 7;
        const float4* kui = (const float4*)(ui_lcu + ((size_t)j*RR + r)*EE);
        const float4* i4  = (const float4*)sm.r.ier;
        float ip_ = 0.f;
        #pragma unroll
        for (int i = 0; i < 4; ++i) {
            int c = l + 8*i;
            ip_ += dot4(kui[c], i4[c]);
        }
        ip_ += __shfl_xor(ip_, 1); ip_ += __shfl_xor(ip_, 2); ip_ += __shfl_xor(ip_, 4);
        if (l == 0) ws_ip[(size_t)bs*RR + r] = ip_;
        return;
    }

    // ---------------- attention path ----------------
    float (*ne)[EE]   = sm.a.ne;
    float (*vbuf)[EE] = sm.a.vbuf;
    float* ue = sm.a.ue;
    float* qs = sm.a.qs;
    float (*attn_s)[SS] = sm.a.attn;
    float* maskadd = sm.a.maskadd;

    const int b = blockIdx.x;

    // ---- phase 1: gathers ----
    if (t < EE) ue[t] = uet[(size_t)user[b]*EE + t];
    for (int idx = t; idx < SS*(EE/4); idx += 256) {
        int s = idx >> 5, c = idx & 31;
        const float4* src = (const float4*)(uet + (size_t)neighbor[b*SS + s]*EE);
        ((float4*)&ne[s][0])[c] = src[c];
    }
    if (t < SS) maskadd[t] = (neighbor[b*SS + t] > 0) ? 0.f : -1e9f;
    __syncthreads();

    // ---- phase 2: q = ue @ wq + bq ----
    if (t < EE) {
        float acc = bq[t];
        #pragma unroll 4
        for (int e = 0; e < EE; ++e) acc = fmaf(ue[e], wq[e*EE + t], acc);
        qs[t] = acc;
    }
    __syncthreads();

    // ---- phase 3: k (folded into logits) and v ----
    {
        const int m  = t >> 7;        // 0 = k, 1 = v (wave-uniform)
        const int r  = t & 127;
        const int cg = r & 31;        // column group: output cols [cg*4, cg*4+3]
        const int sg = r >> 5;        // 0..3, s = i*4+sg
        const float4* w4p = (const float4*)(m ? wv : wk);

        float4 acc[13];
        #pragma unroll
        for (int i = 0; i < 13; ++i) acc[i] = make_float4(0.f,0.f,0.f,0.f);

        for (int e4 = 0; e4 < EE/4; ++e4) {
            float4 w0 = w4p[(e4*4 + 0)*(EE/4) + cg];
            float4 w1 = w4p[(e4*4 + 1)*(EE/4) + cg];
            float4 w2 = w4p[(e4*4 + 2)*(EE/4) + cg];
            float4 w3 = w4p[(e4*4 + 3)*(EE/4) + cg];
            #pragma unroll
            for (int i = 0; i < 13; ++i) {
                int s = i*4 + sg;
                if (s < SS) {
                    float4 nv = ((const float4*)&ne[s][0])[e4];
                    fma4(acc[i], nv.x, w0);
                    fma4(acc[i], nv.y, w1);
                    fma4(acc[i], nv.z, w2);
                    fma4(acc[i], nv.w, w3);
                }
            }
        }

        if (m == 0) {
            float4 q4  = ((const float4*)qs)[cg];
            float4 bk4 = ((const float4*)bk)[cg];
            #pragma unroll
            for (int i = 0; i < 13; ++i) {
                int s = i*4 + sg;
                if (s < SS) {   // wave-uniform guard
                    float4 kk;
                    kk.x = acc[i].x + bk4.x; kk.y = acc[i].y + bk4.y;
                    kk.z = acc[i].z + bk4.z; kk.w = acc[i].w + bk4.w;
                    float p = dot4(kk, q4);
                    p += __shfl_xor(p, 1);
                    p += __shfl_xor(p, 2);
                    if ((cg & 3) == 0) attn_s[cg >> 2][s] = p * 0.25f + maskadd[s];
                }
            }
        } else {
            float4 bv4 = ((const float4*)bv)[cg];
            #pragma unroll
            for (int i = 0; i < 13; ++i) {
                int s = i*4 + sg;
                if (s < SS) {
                    float4 vv;
                    vv.x = acc[i].x + bv4.x; vv.y = acc[i].y + bv4.y;
                    vv.z = acc[i].z + bv4.z; vv.w = acc[i].w + bv4.w;
                    ((float4*)&vbuf[s][0])[cg] = vv;
                }
            }
        }
    }
    __syncthreads();

    // ---- phase 4: softmax over s per head (one wave) ----
    if (t < 64) {
        int h = t >> 3, l = t & 7;
        float mx = -3e38f;
        #pragma unroll
        for (int i = 0; i < 7; ++i) { int s = i*8 + l; if (s < SS) mx = fmaxf(mx, attn_s[h][s]); }
        mx = fmaxf(mx, __shfl_xor(mx, 1));
        mx = fmaxf(mx, __shfl_xor(mx, 2));
        mx = fmaxf(mx, __shfl_xor(mx, 4));
        float ev[7]; float sm_ = 0.f;
        #pragma unroll
        for (int i = 0; i < 7; ++i) {
            int s = i*8 + l; ev[i] = 0.f;
            if (s < SS) { ev[i] = expf(attn_s[h][s] - mx); sm_ += ev[i]; }
        }
        sm_ += __shfl_xor(sm_, 1);
        sm_ += __shfl_xor(sm_, 2);
        sm_ += __shfl_xor(sm_, 4);
        float inv = 1.f / sm_;
        #pragma unroll
        for (int i = 0; i < 7; ++i) { int s = i*8 + l; if (s < SS) attn_s[h][s] = ev[i] * inv; }
    }
    __syncthreads();

    // ---- phase 5: ctx = attn * v (in place) ----
    for (int idx = t; idx < SS*(EE/4); idx += 256) {
        int s = idx >> 5, c = idx & 31;
        int h = c >> 2;
        float a = attn_s[h][s];
        float4 vv = ((float4*)&vbuf[s][0])[c];
        vv.x *= a; vv.y *= a; vv.z *= a; vv.w *= a;
        ((float4*)&vbuf[s][0])[c] = vv;
    }
    __syncthreads();

    // ---- phase 6: ne2 = ctx @ wo + bo -> global ws ----
    {
        const int cg = t & 31;
        const int sg = t >> 5;  // 0..7, s = i*8+sg
        const float4* w4p = (const float4*)wo;
        float4 acc[7];
        #pragma unroll
        for (int i = 0; i < 7; ++i) acc[i] = make_float4(0.f,0.f,0.f,0.f);

        for (int e4 = 0; e4 < EE/4; ++e4) {
            float4 w0 = w4p[(e4*4 + 0)*(EE/4) + cg];
            float4 w1 = w4p[(e4*4 + 1)*(EE/4) + cg];
            float4 w2 = w4p[(e4*4 + 2)*(EE/4) + cg];
            float4 w3 = w4p[(e4*4 + 3)*(EE/4) + cg];
            #pragma unroll
            for (int i = 0; i < 7; ++i) {
                int s = i*8 + sg;
                if (s < SS) {
                    float4 nv = ((const float4*)&vbuf[s][0])[e4];
                    fma4(acc[i], nv.x, w0);
                    fma4(acc[i], nv.y, w1);
                    fma4(acc[i], nv.z, w2);
                    fma4(acc[i], nv.w, w3);
                }
            }
        }
        float4 bo4 = ((const float4*)bo)[cg];
        #pragma unroll
        for (int i = 0; i < 7; ++i) {
            int s = i*8 + sg;
            if (s < SS) {
                float4 o;
                o.x = acc[i].x + bo4.x; o.y = acc[i].y + bo4.y;
                o.z = acc[i].z + bo4.z; o.w = acc[i].w + bo4.w;
                ((float4*)ws_ne2)[((size_t)b*SS + s)*(EE/4) + cg] = o;
            }
        }
    }
}

// -------------------- Kernel 2: neighbor-profile half (sorted) + combine --------------------
__global__ __launch_bounds__(256) void neighbor_kernel(
    const int* __restrict__ neighbor, const int* __restrict__ seq,
    const float* __restrict__ iu_lcu,
    const float* __restrict__ ws_ne2, const float* __restrict__ ws_ip,
    const int* __restrict__ perm,
    float* __restrict__ ws_rating)
{
    __shared__ float ner[EE];
    const int bs = perm[blockIdx.x];
    const int t  = threadIdx.x;

    if (t < EE) ner[t] = ws_ne2[(size_t)bs*EE + t];
    const int j = seq[bs];
    const float w = (neighbor[bs] > 0) ? 1.f : 0.f;
    __syncthreads();

    const int r = t >> 3, l = t & 7;
    const float4* kiu = (const float4*)(iu_lcu + ((size_t)j*RR + r)*EE);
    const float4* n4 = (const float4*)ner;

    float np_ = 0.f;
    #pragma unroll
    for (int i = 0; i < 4; ++i) {
        int c = l + 8*i;
        np_ += dot4(kiu[c], n4[c]);
    }
    np_ += __shfl_xor(np_, 1); np_ += __shfl_xor(np_, 2); np_ += __shfl_xor(np_, 4);

    if (l == 0) ws_rating[(size_t)bs*RR + r] = np_ * ws_ip[(size_t)bs*RR + r] * w;
}

// -------------------- Kernel 3: max over s, FC, softmax --------------------
__global__ __launch_bounds__(64) void head_kernel(
    const float* __restrict__ ws_rating,
    const float* __restrict__ fc_w, const float* __restrict__ fc_b,
    float* __restrict__ out)
{
    __shared__ float urv[RR];
    __shared__ float lg[NC];
    const int b = blockIdx.x, t = threadIdx.x;

    if (t < RR) {
        float m = -3e38f;
        const float* p = ws_rating + (size_t)b*SS*RR + t;
        for (int s = 0; s < SS; ++s) m = fmaxf(m, p[s*RR]);
        urv[t] = m;
    }
    __syncthreads();
    if (t < NC) {
        float acc = fc_b[t];
        #pragma unroll
        for (int r = 0; r < RR; ++r) acc = fmaf(urv[r], fc_w[r*NC + t], acc);
        lg[t] = acc;
    }
    __syncthreads();
    if (t < NC) {
        float mx = lg[0];
        #pragma unroll
        for (int c = 1; c < NC; ++c) mx = fmaxf(mx, lg[c]);
        float sm = 0.f;
        #pragma unroll
        for (int c = 0; c < NC; ++c) sm += expf(lg[c] - mx);
        out[b*NC + t] = expf(lg[t] - mx) / sm;
    }
}

extern "C" void kernel_launch(void* const* d_in, const int* in_sizes, int n_in,
                              void* d_out, int out_size, void* d_ws, size_t ws_size,
                              hipStream_t stream) {
    const int*   user     = (const int*)d_in[0];
    const int*   item     = (const int*)d_in[1];
    const int*   neighbor = (const int*)d_in[2];
    const int*   seq      = (const int*)d_in[3];
    const float* uet      = (const float*)d_in[4];
    const float* iet      = (const float*)d_in[5];
    const float* ui_lcu   = (const float*)d_in[6];
    const float* iu_lcu   = (const float*)d_in[7];
    const float* wq = (const float*)d_in[8];   const float* bq = (const float*)d_in[9];
    const float* wk = (const float*)d_in[10];  const float* bk = (const float*)d_in[11];
    const float* wv = (const float*)d_in[12];  const float* bv = (const float*)d_in[13];
    const float* wo = (const float*)d_in[14];  const float* bo = (const float*)d_in[15];
    const float* fcw = (const float*)d_in[16]; const float* fcb = (const float*)d_in[17];

    float* ws = (float*)d_ws;
    float* ws_ne2    = ws;                                    // B*S*E
    float* ws_ip     = ws_ne2    + (size_t)BB*SS*EE;          // B*S*R
    float* ws_rating = ws_ip     + (size_t)BB*SS*RR;          // B*S*R
    int*   hist      = (int*)(ws_rating + (size_t)BB*SS*RR);  // NSEQ
    int*   perm      = hist + NSEQ;                           // NBS
    float* out = (float*)d_out;

    // ---- counting sort of bs-indices by seq value (L2/L3 locality) ----
    hipMemsetAsync(hist, 0, NSEQ * sizeof(int), stream);
    hipLaunchKernelGGL(hist_kernel, dim3((NBS + 255)/256), dim3(256), 0, stream, seq, hist);
    hipLaunchKernelGGL(scan_kernel, dim3(1), dim3(1024), 0, stream, hist);
    hipLaunchKernelGGL(scatter_kernel, dim3((NBS + 255)/256), dim3(256), 0, stream, seq, hist, perm);

    // ---- fused: attention (blocks 0..511)  ||  item-profile gather (blocks 512..) ----
    hipLaunchKernelGGL(attn_item_kernel, dim3(BB + NBS), dim3(256), 0, stream,
                       user, item, neighbor, seq, uet, iet, ui_lcu,
                       wq, bq, wk, bk, wv, bv, wo, bo, perm, ws_ne2, ws_ip);

    // ---- neighbor-profile half + combine ----
    hipLaunchKernelGGL(neighbor_kernel, dim3(NBS), dim3(256), 0, stream,
                       neighbor, seq, iu_lcu, ws_ne2, ws_ip, perm, ws_rating);

    hipLaunchKernelGGL(head_kernel, dim3(BB), dim3(64), 0, stream,
                       ws_rating, fcw, fcb, out);
}

// Round 3
// 231.215 us; speedup vs baseline: 1.1570x; 1.1570x over previous
//
#include <hip/hip_runtime.h>
#include <hip/hip_bf16.h>
#include <math.h>

#define BB 512
#define SS 50
#define EE 128
#define HH 8
#define RR 32
#define NC 5
#define NSEQ 20000
#define NBS (BB*SS)   // 25600

__device__ __forceinline__ void fma4(float4& a, float s, const float4& w) {
    a.x = fmaf(s, w.x, a.x);
    a.y = fmaf(s, w.y, a.y);
    a.z = fmaf(s, w.z, a.z);
    a.w = fmaf(s, w.w, a.w);
}

__device__ __forceinline__ float dot4(const float4& a, const float4& b) {
    return a.x*b.x + a.y*b.y + a.z*b.z + a.w*b.w;
}

// -------------------- sort kernels: counting sort of bs-indices by seq value --------------------
__global__ __launch_bounds__(256) void hist_kernel(const int* __restrict__ seq,
                                                   int* __restrict__ hist) {
    int i = blockIdx.x * 256 + threadIdx.x;
    if (i < NBS) atomicAdd(&hist[seq[i]], 1);
}

// single block, 1024 threads: exclusive scan of hist[NSEQ] in place
__global__ __launch_bounds__(1024) void scan_kernel(int* __restrict__ hist) {
    const int t = threadIdx.x;
    const int CH = 20;                      // 1024*20 = 20480 >= 20000
    const int base = t * CH;
    int loc[CH];
    int s = 0;
    #pragma unroll
    for (int i = 0; i < CH; ++i) {
        int idx = base + i;
        int v = (idx < NSEQ) ? hist[idx] : 0;
        loc[i] = s; s += v;
    }
    const int lane = t & 63, w = t >> 6;    // 16 waves
    int incl = s;
    #pragma unroll
    for (int off = 1; off < 64; off <<= 1) {
        int n = __shfl_up(incl, off);
        if (lane >= off) incl += n;
    }
    __shared__ int wsum[16];
    if (lane == 63) wsum[w] = incl;
    __syncthreads();
    if (t == 0) {
        int acc = 0;
        #pragma unroll
        for (int k = 0; k < 16; ++k) { int v = wsum[k]; wsum[k] = acc; acc += v; }
    }
    __syncthreads();
    const int excl = incl - s + wsum[w];
    #pragma unroll
    for (int i = 0; i < CH; ++i) {
        int idx = base + i;
        if (idx < NSEQ) hist[idx] = excl + loc[i];
    }
}

__global__ __launch_bounds__(256) void scatter_kernel(const int* __restrict__ seq,
                                                      int* __restrict__ hist,
                                                      int* __restrict__ perm) {
    int i = blockIdx.x * 256 + threadIdx.x;
    if (i < NBS) {
        int pos = atomicAdd(&hist[seq[i]], 1);
        perm[pos] = i;
    }
}

// -------------------- Kernel 1: attention + wo --------------------
// one block per b, 256 threads
__global__ __launch_bounds__(256) void attn_kernel(
    const int* __restrict__ user,
    const int* __restrict__ neighbor,
    const float* __restrict__ uet,
    const float* __restrict__ wq, const float* __restrict__ bq,
    const float* __restrict__ wk, const float* __restrict__ bk,
    const float* __restrict__ wv, const float* __restrict__ bv,
    const float* __restrict__ wo, const float* __restrict__ bo,
    float* __restrict__ ws_ne2)
{
    __shared__ float ne[SS][EE];
    __shared__ float vbuf[SS][EE];
    __shared__ float ue[EE];
    __shared__ float qs[EE];
    __shared__ float attn_s[HH][SS];
    __shared__ float maskadd[SS];

    const int b = blockIdx.x;
    const int t = threadIdx.x;

    // ---- phase 1: gathers ----
    if (t < EE) ue[t] = uet[(size_t)user[b]*EE + t];
    for (int idx = t; idx < SS*(EE/4); idx += 256) {
        int s = idx >> 5, c = idx & 31;
        const float4* src = (const float4*)(uet + (size_t)neighbor[b*SS + s]*EE);
        ((float4*)&ne[s][0])[c] = src[c];
    }
    if (t < SS) maskadd[t] = (neighbor[b*SS + t] > 0) ? 0.f : -1e9f;
    __syncthreads();

    // ---- phase 2: q = ue @ wq + bq ----
    if (t < EE) {
        float acc = bq[t];
        #pragma unroll 4
        for (int e = 0; e < EE; ++e) acc = fmaf(ue[e], wq[e*EE + t], acc);
        qs[t] = acc;
    }
    __syncthreads();

    // ---- phase 3: k (folded into logits) and v ----
    {
        const int m  = t >> 7;        // 0 = k, 1 = v (wave-uniform)
        const int r  = t & 127;
        const int cg = r & 31;        // column group: output cols [cg*4, cg*4+3]
        const int sg = r >> 5;        // 0..3, s = i*4+sg
        const float4* w4p = (const float4*)(m ? wv : wk);

        float4 acc[13];
        #pragma unroll
        for (int i = 0; i < 13; ++i) acc[i] = make_float4(0.f,0.f,0.f,0.f);

        for (int e4 = 0; e4 < EE/4; ++e4) {
            float4 w0 = w4p[(e4*4 + 0)*(EE/4) + cg];
            float4 w1 = w4p[(e4*4 + 1)*(EE/4) + cg];
            float4 w2 = w4p[(e4*4 + 2)*(EE/4) + cg];
            float4 w3 = w4p[(e4*4 + 3)*(EE/4) + cg];
            #pragma unroll
            for (int i = 0; i < 13; ++i) {
                int s = i*4 + sg;
                if (s < SS) {
                    float4 nv = ((const float4*)&ne[s][0])[e4];
                    fma4(acc[i], nv.x, w0);
                    fma4(acc[i], nv.y, w1);
                    fma4(acc[i], nv.z, w2);
                    fma4(acc[i], nv.w, w3);
                }
            }
        }

        if (m == 0) {
            float4 q4  = ((const float4*)qs)[cg];
            float4 bk4 = ((const float4*)bk)[cg];
            #pragma unroll
            for (int i = 0; i < 13; ++i) {
                int s = i*4 + sg;
                if (s < SS) {   // wave-uniform guard
                    float4 kk;
                    kk.x = acc[i].x + bk4.x; kk.y = acc[i].y + bk4.y;
                    kk.z = acc[i].z + bk4.z; kk.w = acc[i].w + bk4.w;
                    float p = dot4(kk, q4);
                    p += __shfl_xor(p, 1);
                    p += __shfl_xor(p, 2);
                    if ((cg & 3) == 0) attn_s[cg >> 2][s] = p * 0.25f + maskadd[s];
                }
            }
        } else {
            float4 bv4 = ((const float4*)bv)[cg];
            #pragma unroll
            for (int i = 0; i < 13; ++i) {
                int s = i*4 + sg;
                if (s < SS) {
                    float4 vv;
                    vv.x = acc[i].x + bv4.x; vv.y = acc[i].y + bv4.y;
                    vv.z = acc[i].z + bv4.z; vv.w = acc[i].w + bv4.w;
                    ((float4*)&vbuf[s][0])[cg] = vv;
                }
            }
        }
    }
    __syncthreads();

    // ---- phase 4: softmax over s per head (one wave) ----
    if (t < 64) {
        int h = t >> 3, l = t & 7;
        float mx = -3e38f;
        #pragma unroll
        for (int i = 0; i < 7; ++i) { int s = i*8 + l; if (s < SS) mx = fmaxf(mx, attn_s[h][s]); }
        mx = fmaxf(mx, __shfl_xor(mx, 1));
        mx = fmaxf(mx, __shfl_xor(mx, 2));
        mx = fmaxf(mx, __shfl_xor(mx, 4));
        float ev[7]; float sm_ = 0.f;
        #pragma unroll
        for (int i = 0; i < 7; ++i) {
            int s = i*8 + l; ev[i] = 0.f;
            if (s < SS) { ev[i] = expf(attn_s[h][s] - mx); sm_ += ev[i]; }
        }
        sm_ += __shfl_xor(sm_, 1);
        sm_ += __shfl_xor(sm_, 2);
        sm_ += __shfl_xor(sm_, 4);
        float inv = 1.f / sm_;
        #pragma unroll
        for (int i = 0; i < 7; ++i) { int s = i*8 + l; if (s < SS) attn_s[h][s] = ev[i] * inv; }
    }
    __syncthreads();

    // ---- phase 5: ctx = attn * v (in place) ----
    for (int idx = t; idx < SS*(EE/4); idx += 256) {
        int s = idx >> 5, c = idx & 31;
        int h = c >> 2;
        float a = attn_s[h][s];
        float4 vv = ((float4*)&vbuf[s][0])[c];
        vv.x *= a; vv.y *= a; vv.z *= a; vv.w *= a;
        ((float4*)&vbuf[s][0])[c] = vv;
    }
    __syncthreads();

    // ---- phase 6: ne2 = ctx @ wo + bo -> global ws ----
    {
        const int cg = t & 31;
        const int sg = t >> 5;  // 0..7, s = i*8+sg
        const float4* w4p = (const float4*)wo;
        float4 acc[7];
        #pragma unroll
        for (int i = 0; i < 7; ++i) acc[i] = make_float4(0.f,0.f,0.f,0.f);

        for (int e4 = 0; e4 < EE/4; ++e4) {
            float4 w0 = w4p[(e4*4 + 0)*(EE/4) + cg];
            float4 w1 = w4p[(e4*4 + 1)*(EE/4) + cg];
            float4 w2 = w4p[(e4*4 + 2)*(EE/4) + cg];
            float4 w3 = w4p[(e4*4 + 3)*(EE/4) + cg];
            #pragma unroll
            for (int i = 0; i < 7; ++i) {
                int s = i*8 + sg;
                if (s < SS) {
                    float4 nv = ((const float4*)&vbuf[s][0])[e4];
                    fma4(acc[i], nv.x, w0);
                    fma4(acc[i], nv.y, w1);
                    fma4(acc[i], nv.z, w2);
                    fma4(acc[i], nv.w, w3);
                }
            }
        }
        float4 bo4 = ((const float4*)bo)[cg];
        #pragma unroll
        for (int i = 0; i < 7; ++i) {
            int s = i*8 + sg;
            if (s < SS) {
                float4 o;
                o.x = acc[i].x + bo4.x; o.y = acc[i].y + bo4.y;
                o.z = acc[i].z + bo4.z; o.w = acc[i].w + bo4.w;
                ((float4*)ws_ne2)[((size_t)b*SS + s)*(EE/4) + cg] = o;
            }
        }
    }
}

// -------------------- Kernel 2: region gather + dots, sorted by seq --------------------
// one block per sorted (b,s), 256 threads; thread (r = t>>3, l = t&7); ~1KB LDS
__global__ __launch_bounds__(256) void region_kernel(
    const int* __restrict__ neighbor, const int* __restrict__ seq,
    const int* __restrict__ item,
    const float* __restrict__ ui_lcu, const float* __restrict__ iu_lcu,
    const float* __restrict__ iet, const float* __restrict__ ws_ne2,
    const int* __restrict__ perm,
    float* __restrict__ ws_rating)
{
    __shared__ float ner[EE], ier[EE];
    const int bs = perm[blockIdx.x];
    const int b  = bs / SS;
    const int t  = threadIdx.x;

    if (t < EE) ner[t] = ws_ne2[(size_t)bs*EE + t];
    else        ier[t - EE] = iet[(size_t)item[b]*EE + (t - EE)];

    const int j  = seq[bs];
    const float w = (neighbor[bs] > 0) ? 1.f : 0.f;
    __syncthreads();

    const int r = t >> 3, l = t & 7;
    const float4* kiu = (const float4*)(iu_lcu + ((size_t)j*RR + r)*EE);
    const float4* kui = (const float4*)(ui_lcu + ((size_t)j*RR + r)*EE);
    const float4* n4 = (const float4*)ner;
    const float4* i4 = (const float4*)ier;

    float np_ = 0.f, ip_ = 0.f;
    #pragma unroll
    for (int i = 0; i < 4; ++i) {
        int c = l + 8*i;
        np_ += dot4(kiu[c], n4[c]);
        ip_ += dot4(kui[c], i4[c]);
    }
    np_ += __shfl_xor(np_, 1); np_ += __shfl_xor(np_, 2); np_ += __shfl_xor(np_, 4);
    ip_ += __shfl_xor(ip_, 1); ip_ += __shfl_xor(ip_, 2); ip_ += __shfl_xor(ip_, 4);

    if (l == 0) ws_rating[(size_t)bs*RR + r] = np_ * ip_ * w;
}

// -------------------- Kernel 3: max over s, FC, softmax --------------------
__global__ __launch_bounds__(64) void head_kernel(
    const float* __restrict__ ws_rating,
    const float* __restrict__ fc_w, const float* __restrict__ fc_b,
    float* __restrict__ out)
{
    __shared__ float urv[RR];
    __shared__ float lg[NC];
    const int b = blockIdx.x, t = threadIdx.x;

    if (t < RR) {
        float m = -3e38f;
        const float* p = ws_rating + (size_t)b*SS*RR + t;
        for (int s = 0; s < SS; ++s) m = fmaxf(m, p[s*RR]);
        urv[t] = m;
    }
    __syncthreads();
    if (t < NC) {
        float acc = fc_b[t];
        #pragma unroll
        for (int r = 0; r < RR; ++r) acc = fmaf(urv[r], fc_w[r*NC + t], acc);
        lg[t] = acc;
    }
    __syncthreads();
    if (t < NC) {
        float mx = lg[0];
        #pragma unroll
        for (int c = 1; c < NC; ++c) mx = fmaxf(mx, lg[c]);
        float sm = 0.f;
        #pragma unroll
        for (int c = 0; c < NC; ++c) sm += expf(lg[c] - mx);
        out[b*NC + t] = expf(lg[t] - mx) / sm;
    }
}

extern "C" void kernel_launch(void* const* d_in, const int* in_sizes, int n_in,
                              void* d_out, int out_size, void* d_ws, size_t ws_size,
                              hipStream_t stream) {
    const int*   user     = (const int*)d_in[0];
    const int*   item     = (const int*)d_in[1];
    const int*   neighbor = (const int*)d_in[2];
    const int*   seq      = (const int*)d_in[3];
    const float* uet      = (const float*)d_in[4];
    const float* iet      = (const float*)d_in[5];
    const float* ui_lcu   = (const float*)d_in[6];
    const float* iu_lcu   = (const float*)d_in[7];
    const float* wq = (const float*)d_in[8];   const float* bq = (const float*)d_in[9];
    const float* wk = (const float*)d_in[10];  const float* bk = (const float*)d_in[11];
    const float* wv = (const float*)d_in[12];  const float* bv = (const float*)d_in[13];
    const float* wo = (const float*)d_in[14];  const float* bo = (const float*)d_in[15];
    const float* fcw = (const float*)d_in[16]; const float* fcb = (const float*)d_in[17];

    float* ws = (float*)d_ws;
    float* ws_ne2    = ws;                                    // B*S*E
    float* ws_rating = ws_ne2    + (size_t)BB*SS*EE;          // B*S*R
    int*   hist      = (int*)(ws_rating + (size_t)BB*SS*RR);  // NSEQ
    int*   perm      = hist + NSEQ;                           // NBS
    float* out = (float*)d_out;

    // ---- counting sort of bs-indices by seq value (L2/L3 locality) ----
    hipMemsetAsync(hist, 0, NSEQ * sizeof(int), stream);
    hipLaunchKernelGGL(hist_kernel, dim3((NBS + 255)/256), dim3(256), 0, stream, seq, hist);
    hipLaunchKernelGGL(scan_kernel, dim3(1), dim3(1024), 0, stream, hist);
    hipLaunchKernelGGL(scatter_kernel, dim3((NBS + 255)/256), dim3(256), 0, stream, seq, hist, perm);

    // ---- attention ----
    hipLaunchKernelGGL(attn_kernel, dim3(BB), dim3(256), 0, stream,
                       user, neighbor, uet,
                       wq, bq, wk, bk, wv, bv, wo, bo, ws_ne2);

    // ---- region (both halves), sorted order ----
    hipLaunchKernelGGL(region_kernel, dim3(NBS), dim3(256), 0, stream,
                       neighbor, seq, item, ui_lcu, iu_lcu, iet, ws_ne2, perm, ws_rating);

    hipLaunchKernelGGL(head_kernel, dim3(BB), dim3(64), 0, stream,
                       ws_rating, fcw, fcb, out);
}

// Round 4
// 230.858 us; speedup vs baseline: 1.1588x; 1.0015x over previous
//
#include <hip/hip_runtime.h>
#include <hip/hip_bf16.h>
#include <math.h>

#define BB 512
#define SS 50
#define EE 128
#define HH 8
#define RR 32
#define NC 5
#define NSEQ 20000
#define NBS (BB*SS)   // 25600

__device__ __forceinline__ void fma4(float4& a, float s, const float4& w) {
    a.x = fmaf(s, w.x, a.x);
    a.y = fmaf(s, w.y, a.y);
    a.z = fmaf(s, w.z, a.z);
    a.w = fmaf(s, w.w, a.w);
}

__device__ __forceinline__ float dot4(const float4& a, const float4& b) {
    return a.x*b.x + a.y*b.y + a.z*b.z + a.w*b.w;
}

// -------------------- counting sort of bs-indices by seq value --------------------
__global__ __launch_bounds__(256) void hist_kernel(const int* __restrict__ seq,
                                                   int* __restrict__ hist) {
    int i = blockIdx.x * 256 + threadIdx.x;
    if (i < NBS) atomicAdd(&hist[seq[i]], 1);
}

// single block, 1024 threads: exclusive scan of hist[NSEQ]; writes working copy
// back to hist AND pristine copy to hstart (with sentinel hstart[NSEQ] = NBS).
__global__ __launch_bounds__(1024) void scan_kernel(int* __restrict__ hist,
                                                    int* __restrict__ hstart) {
    const int t = threadIdx.x;
    const int CH = 20;                      // 1024*20 = 20480 >= 20000
    const int base = t * CH;
    int loc[CH];
    int s = 0;
    #pragma unroll
    for (int i = 0; i < CH; ++i) {
        int idx = base + i;
        int v = (idx < NSEQ) ? hist[idx] : 0;
        loc[i] = s; s += v;
    }
    const int lane = t & 63, w = t >> 6;    // 16 waves
    int incl = s;
    #pragma unroll
    for (int off = 1; off < 64; off <<= 1) {
        int n = __shfl_up(incl, off);
        if (lane >= off) incl += n;
    }
    __shared__ int wsum[16];
    if (lane == 63) wsum[w] = incl;
    __syncthreads();
    if (t == 0) {
        int acc = 0;
        #pragma unroll
        for (int k = 0; k < 16; ++k) { int v = wsum[k]; wsum[k] = acc; acc += v; }
    }
    __syncthreads();
    const int excl = incl - s + wsum[w];
    #pragma unroll
    for (int i = 0; i < CH; ++i) {
        int idx = base + i;
        if (idx < NSEQ) {
            int e = excl + loc[i];
            hist[idx] = e;
            hstart[idx] = e;
        }
    }
    if (t == 0) hstart[NSEQ] = NBS;
}

__global__ __launch_bounds__(256) void scatter_kernel(const int* __restrict__ seq,
                                                      int* __restrict__ hist,
                                                      int* __restrict__ perm) {
    int i = blockIdx.x * 256 + threadIdx.x;
    if (i < NBS) {
        int pos = atomicAdd(&hist[seq[i]], 1);
        perm[pos] = i;
    }
}

// -------------------- Kernel 1: attention + wo (27 KB LDS) --------------------
// one block per b, 256 threads; thread = (cg = t&31 -> 4 output cols, sg = t>>5 -> s mod 8)
__global__ __launch_bounds__(256, 4) void attn_kernel(
    const int* __restrict__ user,
    const int* __restrict__ neighbor,
    const float* __restrict__ uet,
    const float* __restrict__ wq, const float* __restrict__ bq,
    const float* __restrict__ wk, const float* __restrict__ bk,
    const float* __restrict__ wv, const float* __restrict__ bv,
    const float* __restrict__ wo, const float* __restrict__ bo,
    float* __restrict__ ws_ne2)
{
    __shared__ float ne[SS][EE];      // neighbor emb -> later overwritten with v/ctx
    __shared__ float ue[EE];
    __shared__ float qs[EE];
    __shared__ float attn_s[HH][SS];
    __shared__ float maskadd[SS];

    const int b = blockIdx.x;
    const int t = threadIdx.x;

    // ---- gathers ----
    if (t < EE) ue[t] = uet[(size_t)user[b]*EE + t];
    for (int idx = t; idx < SS*(EE/4); idx += 256) {
        int s = idx >> 5, c = idx & 31;
        const float4* src = (const float4*)(uet + (size_t)neighbor[b*SS + s]*EE);
        ((float4*)&ne[s][0])[c] = src[c];
    }
    if (t < SS) maskadd[t] = (neighbor[b*SS + t] > 0) ? 0.f : -1e9f;
    __syncthreads();

    // ---- q = ue @ wq + bq ----
    if (t < EE) {
        float acc = bq[t];
        #pragma unroll 4
        for (int e = 0; e < EE; ++e) acc = fmaf(ue[e], wq[e*EE + t], acc);
        qs[t] = acc;
    }
    __syncthreads();

    const int cg = t & 31;   // float4 column group
    const int sg = t >> 5;   // 0..7

    // ---- k pass: logits folded ----
    {
        const float4* w4p = (const float4*)wk;
        float4 acc[7];
        #pragma unroll
        for (int i = 0; i < 7; ++i) acc[i] = make_float4(0.f,0.f,0.f,0.f);
        for (int e4 = 0; e4 < EE/4; ++e4) {
            float4 w0 = w4p[(e4*4 + 0)*(EE/4) + cg];
            float4 w1 = w4p[(e4*4 + 1)*(EE/4) + cg];
            float4 w2 = w4p[(e4*4 + 2)*(EE/4) + cg];
            float4 w3 = w4p[(e4*4 + 3)*(EE/4) + cg];
            #pragma unroll
            for (int i = 0; i < 7; ++i) {
                int s = i*8 + sg;
                if (s < SS) {
                    float4 nv = ((const float4*)&ne[s][0])[e4];
                    fma4(acc[i], nv.x, w0);
                    fma4(acc[i], nv.y, w1);
                    fma4(acc[i], nv.z, w2);
                    fma4(acc[i], nv.w, w3);
                }
            }
        }
        float4 q4  = ((const float4*)qs)[cg];
        float4 bk4 = ((const float4*)bk)[cg];
        #pragma unroll
        for (int i = 0; i < 7; ++i) {
            int s = i*8 + sg;
            if (s < SS) {   // wave-uniform (sg pairs per wave)
                float4 kk;
                kk.x = acc[i].x + bk4.x; kk.y = acc[i].y + bk4.y;
                kk.z = acc[i].z + bk4.z; kk.w = acc[i].w + bk4.w;
                float p = dot4(kk, q4);
                p += __shfl_xor(p, 1);
                p += __shfl_xor(p, 2);
                if ((cg & 3) == 0) attn_s[cg >> 2][s] = p * 0.25f + maskadd[s];
            }
        }
    }

    // ---- v pass (into registers), then overwrite ne with v ----
    {
        const float4* w4p = (const float4*)wv;
        float4 acc[7];
        #pragma unroll
        for (int i = 0; i < 7; ++i) acc[i] = make_float4(0.f,0.f,0.f,0.f);
        for (int e4 = 0; e4 < EE/4; ++e4) {
            float4 w0 = w4p[(e4*4 + 0)*(EE/4) + cg];
            float4 w1 = w4p[(e4*4 + 1)*(EE/4) + cg];
            float4 w2 = w4p[(e4*4 + 2)*(EE/4) + cg];
            float4 w3 = w4p[(e4*4 + 3)*(EE/4) + cg];
            #pragma unroll
            for (int i = 0; i < 7; ++i) {
                int s = i*8 + sg;
                if (s < SS) {
                    float4 nv = ((const float4*)&ne[s][0])[e4];
                    fma4(acc[i], nv.x, w0);
                    fma4(acc[i], nv.y, w1);
                    fma4(acc[i], nv.z, w2);
                    fma4(acc[i], nv.w, w3);
                }
            }
        }
        __syncthreads();   // all reads of ne done (k & v passes), attn_s written
        float4 bv4 = ((const float4*)bv)[cg];
        #pragma unroll
        for (int i = 0; i < 7; ++i) {
            int s = i*8 + sg;
            if (s < SS) {
                float4 vv;
                vv.x = acc[i].x + bv4.x; vv.y = acc[i].y + bv4.y;
                vv.z = acc[i].z + bv4.z; vv.w = acc[i].w + bv4.w;
                ((float4*)&ne[s][0])[cg] = vv;
            }
        }
    }
    __syncthreads();

    // ---- softmax over s per head (one wave) ----
    if (t < 64) {
        int h = t >> 3, l = t & 7;
        float mx = -3e38f;
        #pragma unroll
        for (int i = 0; i < 7; ++i) { int s = i*8 + l; if (s < SS) mx = fmaxf(mx, attn_s[h][s]); }
        mx = fmaxf(mx, __shfl_xor(mx, 1));
        mx = fmaxf(mx, __shfl_xor(mx, 2));
        mx = fmaxf(mx, __shfl_xor(mx, 4));
        float ev[7]; float sm_ = 0.f;
        #pragma unroll
        for (int i = 0; i < 7; ++i) {
            int s = i*8 + l; ev[i] = 0.f;
            if (s < SS) { ev[i] = expf(attn_s[h][s] - mx); sm_ += ev[i]; }
        }
        sm_ += __shfl_xor(sm_, 1);
        sm_ += __shfl_xor(sm_, 2);
        sm_ += __shfl_xor(sm_, 4);
        float inv = 1.f / sm_;
        #pragma unroll
        for (int i = 0; i < 7; ++i) { int s = i*8 + l; if (s < SS) attn_s[h][s] = ev[i] * inv; }
    }
    __syncthreads();

    // ---- ctx = attn * v (in place in ne) ----
    for (int idx = t; idx < SS*(EE/4); idx += 256) {
        int s = idx >> 5, c = idx & 31;
        int h = c >> 2;
        float a = attn_s[h][s];
        float4 vv = ((float4*)&ne[s][0])[c];
        vv.x *= a; vv.y *= a; vv.z *= a; vv.w *= a;
        ((float4*)&ne[s][0])[c] = vv;
    }
    __syncthreads();

    // ---- ne2 = ctx @ wo + bo -> global ws ----
    {
        const float4* w4p = (const float4*)wo;
        float4 acc[7];
        #pragma unroll
        for (int i = 0; i < 7; ++i) acc[i] = make_float4(0.f,0.f,0.f,0.f);
        for (int e4 = 0; e4 < EE/4; ++e4) {
            float4 w0 = w4p[(e4*4 + 0)*(EE/4) + cg];
            float4 w1 = w4p[(e4*4 + 1)*(EE/4) + cg];
            float4 w2 = w4p[(e4*4 + 2)*(EE/4) + cg];
            float4 w3 = w4p[(e4*4 + 3)*(EE/4) + cg];
            #pragma unroll
            for (int i = 0; i < 7; ++i) {
                int s = i*8 + sg;
                if (s < SS) {
                    float4 nv = ((const float4*)&ne[s][0])[e4];
                    fma4(acc[i], nv.x, w0);
                    fma4(acc[i], nv.y, w1);
                    fma4(acc[i], nv.z, w2);
                    fma4(acc[i], nv.w, w3);
                }
            }
        }
        float4 bo4 = ((const float4*)bo)[cg];
        #pragma unroll
        for (int i = 0; i < 7; ++i) {
            int s = i*8 + sg;
            if (s < SS) {
                float4 o;
                o.x = acc[i].x + bo4.x; o.y = acc[i].y + bo4.y;
                o.z = acc[i].z + bo4.z; o.w = acc[i].w + bo4.w;
                ((float4*)ws_ne2)[((size_t)b*SS + s)*(EE/4) + cg] = o;
            }
        }
    }
}

// -------------------- Kernel 2: per-unique-j region (K rows read ONCE) --------------------
// one block per j in [0, NSEQ); K_iu/K_ui rows held in registers; loop over occurrences
__global__ __launch_bounds__(256, 6) void region_kernel(
    const int* __restrict__ neighbor, const int* __restrict__ item,
    const float* __restrict__ ui_lcu, const float* __restrict__ iu_lcu,
    const float* __restrict__ iet, const float* __restrict__ ws_ne2,
    const int* __restrict__ hstart, const int* __restrict__ perm,
    float* __restrict__ ws_rating)
{
    const int j = blockIdx.x;
    const int start = hstart[j];
    const int end   = hstart[j + 1];
    if (start >= end) return;

    const int t = threadIdx.x;
    const int r = t >> 3, l = t & 7;

    // load this j's K rows into registers (32 VGPRs): row r, float4 chunks l+8i
    const float4* kiu_g = (const float4*)(iu_lcu + ((size_t)j*RR + r)*EE);
    const float4* kui_g = (const float4*)(ui_lcu + ((size_t)j*RR + r)*EE);
    float4 kiu_r[4], kui_r[4];
    #pragma unroll
    for (int i = 0; i < 4; ++i) {
        int c = l + 8*i;
        kiu_r[i] = kiu_g[c];
        kui_r[i] = kui_g[c];
    }

    __shared__ float ner[EE], ier[EE];
    const float4* n4 = (const float4*)ner;
    const float4* i4 = (const float4*)ier;

    for (int o = start; o < end; ++o) {
        const int bs = perm[o];
        const int b  = bs / SS;
        if (t < EE) ner[t] = ws_ne2[(size_t)bs*EE + t];
        else        ier[t - EE] = iet[(size_t)item[b]*EE + (t - EE)];
        __syncthreads();

        float np_ = 0.f, ip_ = 0.f;
        #pragma unroll
        for (int i = 0; i < 4; ++i) {
            int c = l + 8*i;
            np_ += dot4(kiu_r[i], n4[c]);
            ip_ += dot4(kui_r[i], i4[c]);
        }
        np_ += __shfl_xor(np_, 1); np_ += __shfl_xor(np_, 2); np_ += __shfl_xor(np_, 4);
        ip_ += __shfl_xor(ip_, 1); ip_ += __shfl_xor(ip_, 2); ip_ += __shfl_xor(ip_, 4);

        const float w = (neighbor[bs] > 0) ? 1.f : 0.f;
        if (l == 0) ws_rating[(size_t)bs*RR + r] = np_ * ip_ * w;
        if (o + 1 < end) __syncthreads();
    }
}

// -------------------- Kernel 3: max over s, FC, softmax --------------------
__global__ __launch_bounds__(64) void head_kernel(
    const float* __restrict__ ws_rating,
    const float* __restrict__ fc_w, const float* __restrict__ fc_b,
    float* __restrict__ out)
{
    __shared__ float urv[RR];
    __shared__ float lg[NC];
    const int b = blockIdx.x, t = threadIdx.x;

    if (t < RR) {
        float m = -3e38f;
        const float* p = ws_rating + (size_t)b*SS*RR + t;
        for (int s = 0; s < SS; ++s) m = fmaxf(m, p[s*RR]);
        urv[t] = m;
    }
    __syncthreads();
    if (t < NC) {
        float acc = fc_b[t];
        #pragma unroll
        for (int r = 0; r < RR; ++r) acc = fmaf(urv[r], fc_w[r*NC + t], acc);
        lg[t] = acc;
    }
    __syncthreads();
    if (t < NC) {
        float mx = lg[0];
        #pragma unroll
        for (int c = 1; c < NC; ++c) mx = fmaxf(mx, lg[c]);
        float sm = 0.f;
        #pragma unroll
        for (int c = 0; c < NC; ++c) sm += expf(lg[c] - mx);
        out[b*NC + t] = expf(lg[t] - mx) / sm;
    }
}

extern "C" void kernel_launch(void* const* d_in, const int* in_sizes, int n_in,
                              void* d_out, int out_size, void* d_ws, size_t ws_size,
                              hipStream_t stream) {
    const int*   user     = (const int*)d_in[0];
    const int*   item     = (const int*)d_in[1];
    const int*   neighbor = (const int*)d_in[2];
    const int*   seq      = (const int*)d_in[3];
    const float* uet      = (const float*)d_in[4];
    const float* iet      = (const float*)d_in[5];
    const float* ui_lcu   = (const float*)d_in[6];
    const float* iu_lcu   = (const float*)d_in[7];
    const float* wq = (const float*)d_in[8];   const float* bq = (const float*)d_in[9];
    const float* wk = (const float*)d_in[10];  const float* bk = (const float*)d_in[11];
    const float* wv = (const float*)d_in[12];  const float* bv = (const float*)d_in[13];
    const float* wo = (const float*)d_in[14];  const float* bo = (const float*)d_in[15];
    const float* fcw = (const float*)d_in[16]; const float* fcb = (const float*)d_in[17];

    float* ws = (float*)d_ws;
    float* ws_ne2    = ws;                                    // B*S*E
    float* ws_rating = ws_ne2    + (size_t)BB*SS*EE;          // B*S*R
    int*   hist      = (int*)(ws_rating + (size_t)BB*SS*RR);  // NSEQ (working)
    int*   hstart    = hist + NSEQ;                           // NSEQ+1 (pristine + sentinel)
    int*   perm      = hstart + NSEQ + 1;                     // NBS
    float* out = (float*)d_out;

    // ---- counting sort: group (b,s) indices by seq value ----
    hipMemsetAsync(hist, 0, NSEQ * sizeof(int), stream);
    hipLaunchKernelGGL(hist_kernel, dim3((NBS + 255)/256), dim3(256), 0, stream, seq, hist);
    hipLaunchKernelGGL(scan_kernel, dim3(1), dim3(1024), 0, stream, hist, hstart);
    hipLaunchKernelGGL(scatter_kernel, dim3((NBS + 255)/256), dim3(256), 0, stream, seq, hist, perm);

    // ---- attention ----
    hipLaunchKernelGGL(attn_kernel, dim3(BB), dim3(256), 0, stream,
                       user, neighbor, uet,
                       wq, bq, wk, bk, wv, bv, wo, bo, ws_ne2);

    // ---- region: one block per unique seq value ----
    hipLaunchKernelGGL(region_kernel, dim3(NSEQ), dim3(256), 0, stream,
                       neighbor, item, ui_lcu, iu_lcu, iet, ws_ne2, hstart, perm, ws_rating);

    hipLaunchKernelGGL(head_kernel, dim3(BB), dim3(64), 0, stream,
                       ws_rating, fcw, fcb, out);
}

// Round 5
// 182.898 us; speedup vs baseline: 1.4627x; 1.2622x over previous
//
#include <hip/hip_runtime.h>
#include <math.h>

#define BB 512
#define SS 50
#define EE 128
#define HH 8
#define RR 32
#define NC 5
#define NSEQ 20000
#define NBS (BB*SS)   // 25600
#define LDK 136       // padded bf16 row stride (ushorts) for LDS A-tile

typedef __attribute__((ext_vector_type(8))) __bf16 bf16x8;
typedef __attribute__((ext_vector_type(4))) float f32x4;
typedef __attribute__((ext_vector_type(4))) unsigned short us4;

__device__ __forceinline__ unsigned short f2bf(float f) {
    unsigned int u = __float_as_uint(f);
    unsigned int r = (u + 0x7fffu + ((u >> 16) & 1u)) >> 16;
    return (unsigned short)r;
}
__device__ __forceinline__ float bf2f(unsigned short s) {
    return __uint_as_float(((unsigned int)s) << 16);
}
__device__ __forceinline__ float dot4(const float4& a, const float4& b) {
    return a.x*b.x + a.y*b.y + a.z*b.z + a.w*b.w;
}

// -------------------- weight transpose + bf16 convert --------------------
// grid 256 blocks x 128 thr: blocks [0,128) -> wv, [128,256) -> wo; out[n][k] = in[k][n]
__global__ __launch_bounds__(128) void conv_kernel(const float* __restrict__ wv,
                                                   const float* __restrict__ wo,
                                                   unsigned short* __restrict__ wvT,
                                                   unsigned short* __restrict__ woT) {
    const int n = blockIdx.x & 127;
    const float* src = (blockIdx.x >> 7) ? wo : wv;
    unsigned short* dst = (blockIdx.x >> 7) ? woT : wvT;
    const int k = threadIdx.x;
    dst[n*EE + k] = f2bf(src[k*EE + n]);
}

// -------------------- counting sort of bs-indices by seq value --------------------
__global__ __launch_bounds__(256) void hist_kernel(const int* __restrict__ seq,
                                                   int* __restrict__ hist) {
    int i = blockIdx.x * 256 + threadIdx.x;
    if (i < NBS) atomicAdd(&hist[seq[i]], 1);
}

__global__ __launch_bounds__(1024) void scan_kernel(int* __restrict__ hist,
                                                    int* __restrict__ hstart) {
    const int t = threadIdx.x;
    const int CH = 20;
    const int base = t * CH;
    int loc[CH];
    int s = 0;
    #pragma unroll
    for (int i = 0; i < CH; ++i) {
        int idx = base + i;
        int v = (idx < NSEQ) ? hist[idx] : 0;
        loc[i] = s; s += v;
    }
    const int lane = t & 63, w = t >> 6;
    int incl = s;
    #pragma unroll
    for (int off = 1; off < 64; off <<= 1) {
        int n = __shfl_up(incl, off);
        if (lane >= off) incl += n;
    }
    __shared__ int wsum[16];
    if (lane == 63) wsum[w] = incl;
    __syncthreads();
    if (t == 0) {
        int acc = 0;
        #pragma unroll
        for (int k = 0; k < 16; ++k) { int v = wsum[k]; wsum[k] = acc; acc += v; }
    }
    __syncthreads();
    const int excl = incl - s + wsum[w];
    #pragma unroll
    for (int i = 0; i < CH; ++i) {
        int idx = base + i;
        if (idx < NSEQ) {
            int e = excl + loc[i];
            hist[idx] = e;
            hstart[idx] = e;
        }
    }
    if (t == 0) hstart[NSEQ] = NBS;
}

__global__ __launch_bounds__(256) void scatter_kernel(const int* __restrict__ seq,
                                                      int* __restrict__ hist,
                                                      int* __restrict__ perm) {
    int i = blockIdx.x * 256 + threadIdx.x;
    if (i < NBS) {
        int pos = atomicAdd(&hist[seq[i]], 1);
        perm[pos] = i;
    }
}

// -------------------- Kernel 1: attention via qkvec-trick + MFMA GEMMs --------------------
// one block per b, 256 threads (4 waves)
__global__ __launch_bounds__(256, 4) void attn_kernel(
    const int* __restrict__ user,
    const int* __restrict__ neighbor,
    const float* __restrict__ uet,
    const float* __restrict__ wq, const float* __restrict__ bq,
    const float* __restrict__ wk, const float* __restrict__ bk,
    const float* __restrict__ bv, const float* __restrict__ bo,
    const unsigned short* __restrict__ wvT, const unsigned short* __restrict__ woT,
    float* __restrict__ ws_ne2)
{
    __shared__ unsigned short kA[64*LDK];   // ne (bf16) -> ctx (bf16), padded stride
    __shared__ float ue[EE];
    __shared__ float qs[EE];
    __shared__ float qkv[EE][HH];
    __shared__ float qkb[HH];
    __shared__ float attn_s[HH][SS];
    __shared__ float maskadd[SS];

    const int b = blockIdx.x;
    const int t = threadIdx.x;

    // ---- gathers: ue (f32), ne -> bf16 LDS, mask ----
    if (t < EE) ue[t] = uet[(size_t)user[b]*EE + t];
    if (t < SS) maskadd[t] = (neighbor[b*SS + t] > 0) ? 0.f : -1e9f;
    for (int idx = t; idx < SS*32; idx += 256) {
        int s = idx >> 5, g = idx & 31;   // g-th float4 of the row
        float4 v = ((const float4*)(uet + (size_t)neighbor[b*SS + s]*EE))[g];
        us4 o; o.x = f2bf(v.x); o.y = f2bf(v.y); o.z = f2bf(v.z); o.w = f2bf(v.w);
        *(us4*)&kA[s*LDK + g*4] = o;
    }
    for (int idx = t; idx < 14*LDK; idx += 256) {   // zero pad rows 50..63
        kA[50*LDK + idx] = 0;
    }
    __syncthreads();

    // ---- q = ue @ wq + bq ----
    if (t < EE) {
        float acc = bq[t];
        #pragma unroll 4
        for (int e = 0; e < EE; ++e) acc = fmaf(ue[e], wq[e*EE + t], acc);
        qs[t] = acc;
    }
    __syncthreads();

    // ---- qkvec[h] = Wk_h @ q_h ;  qkb[h] = q_h . bk_h ----
    {
        const int e = t >> 1, h0 = (t & 1) * 4;
        const float* wrow = wk + e*EE;
        #pragma unroll
        for (int j = 0; j < 4; ++j) {
            int h = h0 + j;
            float acc = 0.f;
            #pragma unroll
            for (int d = 0; d < 16; ++d) acc = fmaf(qs[h*16 + d], wrow[h*16 + d], acc);
            qkv[e][h] = acc;
        }
    }
    if (t < HH) {
        float acc = 0.f;
        #pragma unroll
        for (int d = 0; d < 16; ++d) acc = fmaf(qs[t*16 + d], bk[t*16 + d], acc);
        qkb[t] = acc;
    }
    __syncthreads();

    // ---- logits[h][s] = (ne[s] . qkvec[h] + qkb[h]) / 4 + mask ----
    if (t < HH*SS) {
        const int s = t >> 3, h = t & 7;
        float acc = 0.f;
        for (int e = 0; e < EE; ++e) {
            acc = fmaf(bf2f(kA[s*LDK + e]), qkv[e][h], acc);
        }
        attn_s[h][s] = (acc + qkb[h]) * 0.25f + maskadd[s];
    }
    __syncthreads();

    // ---- softmax over s per head (one wave) ----
    if (t < 64) {
        int h = t >> 3, l = t & 7;
        float mx = -3e38f;
        #pragma unroll
        for (int i = 0; i < 7; ++i) { int s = i*8 + l; if (s < SS) mx = fmaxf(mx, attn_s[h][s]); }
        mx = fmaxf(mx, __shfl_xor(mx, 1));
        mx = fmaxf(mx, __shfl_xor(mx, 2));
        mx = fmaxf(mx, __shfl_xor(mx, 4));
        float ev[7]; float sm_ = 0.f;
        #pragma unroll
        for (int i = 0; i < 7; ++i) {
            int s = i*8 + l; ev[i] = 0.f;
            if (s < SS) { ev[i] = expf(attn_s[h][s] - mx); sm_ += ev[i]; }
        }
        sm_ += __shfl_xor(sm_, 1);
        sm_ += __shfl_xor(sm_, 2);
        sm_ += __shfl_xor(sm_, 4);
        float inv = 1.f / sm_;
        #pragma unroll
        for (int i = 0; i < 7; ++i) { int s = i*8 + l; if (s < SS) attn_s[h][s] = ev[i] * inv; }
    }
    __syncthreads();

    // ---- MFMA GEMM1: v = ne @ wv ; ctx = (v + bv) * attn -> bf16 (in place, own rows) ----
    const int w    = t >> 6;       // wave id -> row tile [16w, 16w+16)
    const int l    = t & 63;
    const int lrow = l & 15;
    const int kg   = l >> 4;       // 0..3

    bf16x8 a0 = *(const bf16x8*)&kA[(w*16 + lrow)*LDK +  0 + kg*8];
    bf16x8 a1 = *(const bf16x8*)&kA[(w*16 + lrow)*LDK + 32 + kg*8];
    bf16x8 a2 = *(const bf16x8*)&kA[(w*16 + lrow)*LDK + 64 + kg*8];
    bf16x8 a3 = *(const bf16x8*)&kA[(w*16 + lrow)*LDK + 96 + kg*8];

    f32x4 acc[8];
    #pragma unroll
    for (int nt = 0; nt < 8; ++nt) {
        const unsigned short* bp = wvT + (nt*16 + lrow)*EE + kg*8;
        bf16x8 b0 = *(const bf16x8*)&bp[0];
        bf16x8 b1 = *(const bf16x8*)&bp[32];
        bf16x8 b2 = *(const bf16x8*)&bp[64];
        bf16x8 b3 = *(const bf16x8*)&bp[96];
        f32x4 c = {0.f, 0.f, 0.f, 0.f};
        c = __builtin_amdgcn_mfma_f32_16x16x32_bf16(a0, b0, c, 0, 0, 0);
        c = __builtin_amdgcn_mfma_f32_16x16x32_bf16(a1, b1, c, 0, 0, 0);
        c = __builtin_amdgcn_mfma_f32_16x16x32_bf16(a2, b2, c, 0, 0, 0);
        c = __builtin_amdgcn_mfma_f32_16x16x32_bf16(a3, b3, c, 0, 0, 0);
        acc[nt] = c;
    }

    #pragma unroll
    for (int nt = 0; nt < 8; ++nt) {
        const int col = nt*16 + lrow;
        const float bvc = bv[col];
        #pragma unroll
        for (int rg = 0; rg < 4; ++rg) {
            const int row = w*16 + kg*4 + rg;
            const float av = (row < SS) ? attn_s[nt][row] : 0.f;
            kA[row*LDK + col] = f2bf((acc[nt][rg] + bvc) * av);
        }
    }
    __syncthreads();

    // ---- MFMA GEMM2: ne2 = ctx @ wo + bo -> global ----
    bf16x8 c0 = *(const bf16x8*)&kA[(w*16 + lrow)*LDK +  0 + kg*8];
    bf16x8 c1 = *(const bf16x8*)&kA[(w*16 + lrow)*LDK + 32 + kg*8];
    bf16x8 c2 = *(const bf16x8*)&kA[(w*16 + lrow)*LDK + 64 + kg*8];
    bf16x8 c3 = *(const bf16x8*)&kA[(w*16 + lrow)*LDK + 96 + kg*8];

    #pragma unroll
    for (int nt = 0; nt < 8; ++nt) {
        const unsigned short* bp = woT + (nt*16 + lrow)*EE + kg*8;
        bf16x8 b0 = *(const bf16x8*)&bp[0];
        bf16x8 b1 = *(const bf16x8*)&bp[32];
        bf16x8 b2 = *(const bf16x8*)&bp[64];
        bf16x8 b3 = *(const bf16x8*)&bp[96];
        f32x4 c = {0.f, 0.f, 0.f, 0.f};
        c = __builtin_amdgcn_mfma_f32_16x16x32_bf16(c0, b0, c, 0, 0, 0);
        c = __builtin_amdgcn_mfma_f32_16x16x32_bf16(c1, b1, c, 0, 0, 0);
        c = __builtin_amdgcn_mfma_f32_16x16x32_bf16(c2, b2, c, 0, 0, 0);
        c = __builtin_amdgcn_mfma_f32_16x16x32_bf16(c3, b3, c, 0, 0, 0);
        const int col = nt*16 + lrow;
        const float boc = bo[col];
        #pragma unroll
        for (int rg = 0; rg < 4; ++rg) {
            const int row = w*16 + kg*4 + rg;
            if (row < SS)
                ws_ne2[((size_t)b*SS + row)*EE + col] = c[rg] + boc;
        }
    }
}

// -------------------- Kernel 2: per-unique-j region (K rows read ONCE) --------------------
__global__ __launch_bounds__(256, 6) void region_kernel(
    const int* __restrict__ neighbor, const int* __restrict__ item,
    const float* __restrict__ ui_lcu, const float* __restrict__ iu_lcu,
    const float* __restrict__ iet, const float* __restrict__ ws_ne2,
    const int* __restrict__ hstart, const int* __restrict__ perm,
    float* __restrict__ ws_rating)
{
    const int j = blockIdx.x;
    const int start = hstart[j];
    const int end   = hstart[j + 1];
    if (start >= end) return;

    const int t = threadIdx.x;
    const int r = t >> 3, l = t & 7;

    const float4* kiu_g = (const float4*)(iu_lcu + ((size_t)j*RR + r)*EE);
    const float4* kui_g = (const float4*)(ui_lcu + ((size_t)j*RR + r)*EE);
    float4 kiu_r[4], kui_r[4];
    #pragma unroll
    for (int i = 0; i < 4; ++i) {
        int c = l + 8*i;
        kiu_r[i] = kiu_g[c];
        kui_r[i] = kui_g[c];
    }

    __shared__ float ner[EE], ier[EE];
    const float4* n4 = (const float4*)ner;
    const float4* i4 = (const float4*)ier;

    for (int o = start; o < end; ++o) {
        const int bs = perm[o];
        const int b  = bs / SS;
        if (t < EE) ner[t] = ws_ne2[(size_t)bs*EE + t];
        else        ier[t - EE] = iet[(size_t)item[b]*EE + (t - EE)];
        __syncthreads();

        float np_ = 0.f, ip_ = 0.f;
        #pragma unroll
        for (int i = 0; i < 4; ++i) {
            int c = l + 8*i;
            np_ += dot4(kiu_r[i], n4[c]);
            ip_ += dot4(kui_r[i], i4[c]);
        }
        np_ += __shfl_xor(np_, 1); np_ += __shfl_xor(np_, 2); np_ += __shfl_xor(np_, 4);
        ip_ += __shfl_xor(ip_, 1); ip_ += __shfl_xor(ip_, 2); ip_ += __shfl_xor(ip_, 4);

        const float w = (neighbor[bs] > 0) ? 1.f : 0.f;
        if (l == 0) ws_rating[(size_t)bs*RR + r] = np_ * ip_ * w;
        if (o + 1 < end) __syncthreads();
    }
}

// -------------------- Kernel 3: max over s, FC, softmax (coalesced) --------------------
__global__ __launch_bounds__(256) void head_kernel(
    const float* __restrict__ ws_rating,
    const float* __restrict__ fc_w, const float* __restrict__ fc_b,
    float* __restrict__ out)
{
    __shared__ float part[8][RR];
    __shared__ float urv[RR];
    __shared__ float lg[NC];
    const int b = blockIdx.x, t = threadIdx.x;
    const int r = t & 31, sub = t >> 5;

    float m = -3e38f;
    for (int s = sub; s < SS; s += 8)
        m = fmaxf(m, ws_rating[((size_t)b*SS + s)*RR + r]);
    part[sub][r] = m;
    __syncthreads();
    if (t < RR) {
        float mm = part[0][t];
        #pragma unroll
        for (int k = 1; k < 8; ++k) mm = fmaxf(mm, part[k][t]);
        urv[t] = mm;
    }
    __syncthreads();
    if (t < NC) {
        float acc = fc_b[t];
        #pragma unroll
        for (int rr = 0; rr < RR; ++rr) acc = fmaf(urv[rr], fc_w[rr*NC + t], acc);
        lg[t] = acc;
    }
    __syncthreads();
    if (t < NC) {
        float mx = lg[0];
        #pragma unroll
        for (int c = 1; c < NC; ++c) mx = fmaxf(mx, lg[c]);
        float sm = 0.f;
        #pragma unroll
        for (int c = 0; c < NC; ++c) sm += expf(lg[c] - mx);
        out[b*NC + t] = expf(lg[t] - mx) / sm;
    }
}

extern "C" void kernel_launch(void* const* d_in, const int* in_sizes, int n_in,
                              void* d_out, int out_size, void* d_ws, size_t ws_size,
                              hipStream_t stream) {
    const int*   user     = (const int*)d_in[0];
    const int*   item     = (const int*)d_in[1];
    const int*   neighbor = (const int*)d_in[2];
    const int*   seq      = (const int*)d_in[3];
    const float* uet      = (const float*)d_in[4];
    const float* iet      = (const float*)d_in[5];
    const float* ui_lcu   = (const float*)d_in[6];
    const float* iu_lcu   = (const float*)d_in[7];
    const float* wq = (const float*)d_in[8];   const float* bq = (const float*)d_in[9];
    const float* wk = (const float*)d_in[10];  const float* bk = (const float*)d_in[11];
    const float* wv = (const float*)d_in[12];  const float* bv = (const float*)d_in[13];
    const float* wo = (const float*)d_in[14];  const float* bo = (const float*)d_in[15];
    const float* fcw = (const float*)d_in[16]; const float* fcb = (const float*)d_in[17];

    float* ws = (float*)d_ws;
    float* ws_ne2    = ws;                                       // B*S*E f32
    float* ws_rating = ws_ne2 + (size_t)BB*SS*EE;                // B*S*R f32
    unsigned short* wvT = (unsigned short*)(ws_rating + (size_t)BB*SS*RR);  // 128*128 bf16
    unsigned short* woT = wvT + EE*EE;                           // 128*128 bf16
    int*   hist      = (int*)(woT + EE*EE);                      // NSEQ
    int*   hstart    = hist + NSEQ;                              // NSEQ+1
    int*   perm      = hstart + NSEQ + 1;                        // NBS
    float* out = (float*)d_out;

    // ---- weight transpose/convert + counting sort (independent prep) ----
    hipLaunchKernelGGL(conv_kernel, dim3(256), dim3(128), 0, stream, wv, wo, wvT, woT);
    hipMemsetAsync(hist, 0, NSEQ * sizeof(int), stream);
    hipLaunchKernelGGL(hist_kernel, dim3((NBS + 255)/256), dim3(256), 0, stream, seq, hist);
    hipLaunchKernelGGL(scan_kernel, dim3(1), dim3(1024), 0, stream, hist, hstart);
    hipLaunchKernelGGL(scatter_kernel, dim3((NBS + 255)/256), dim3(256), 0, stream, seq, hist, perm);

    // ---- attention (MFMA) ----
    hipLaunchKernelGGL(attn_kernel, dim3(BB), dim3(256), 0, stream,
                       user, neighbor, uet,
                       wq, bq, wk, bk, bv, bo, wvT, woT, ws_ne2);

    // ---- region: one block per unique seq value ----
    hipLaunchKernelGGL(region_kernel, dim3(NSEQ), dim3(256), 0, stream,
                       neighbor, item, ui_lcu, iu_lcu, iet, ws_ne2, hstart, perm, ws_rating);

    hipLaunchKernelGGL(head_kernel, dim3(BB), dim3(256), 0, stream,
                       ws_rating, fcw, fcb, out);
}

// Round 6
// 175.644 us; speedup vs baseline: 1.5231x; 1.0413x over previous
//
#include <hip/hip_runtime.h>
#include <math.h>

#define BB 512
#define SS 50
#define EE 128
#define HH 8
#define RR 32
#define NC 5
#define NSEQ 20000
#define NBS (BB*SS)   // 25600
#define LDK 136       // padded bf16 row stride (ushorts) for LDS A-tile

typedef __attribute__((ext_vector_type(8))) __bf16 bf16x8;
typedef __attribute__((ext_vector_type(4))) float f32x4;
typedef __attribute__((ext_vector_type(4))) unsigned short us4;

__device__ __forceinline__ unsigned short f2bf(float f) {
    unsigned int u = __float_as_uint(f);
    unsigned int r = (u + 0x7fffu + ((u >> 16) & 1u)) >> 16;
    return (unsigned short)r;
}
__device__ __forceinline__ float dot4(const float4& a, const float4& b) {
    return a.x*b.x + a.y*b.y + a.z*b.z + a.w*b.w;
}
__device__ __forceinline__ float dot4v(const f32x4& a, const float4& b) {
    return a[0]*b.x + a[1]*b.y + a[2]*b.z + a[3]*b.w;
}

// -------------------- weight transpose + bf16 convert --------------------
__global__ __launch_bounds__(128) void conv_kernel(const float* __restrict__ wv,
                                                   const float* __restrict__ wo,
                                                   unsigned short* __restrict__ wvT,
                                                   unsigned short* __restrict__ woT) {
    const int n = blockIdx.x & 127;
    const float* src = (blockIdx.x >> 7) ? wo : wv;
    unsigned short* dst = (blockIdx.x >> 7) ? woT : wvT;
    const int k = threadIdx.x;
    dst[n*EE + k] = f2bf(src[k*EE + n]);
}

// -------------------- counting sort of bs-indices by seq value --------------------
__global__ __launch_bounds__(256) void hist_kernel(const int* __restrict__ seq,
                                                   int* __restrict__ hist) {
    int i = blockIdx.x * 256 + threadIdx.x;
    if (i < NBS) atomicAdd(&hist[seq[i]], 1);
}

__global__ __launch_bounds__(1024) void scan_kernel(int* __restrict__ hist,
                                                    int* __restrict__ hstart) {
    const int t = threadIdx.x;
    const int CH = 20;
    const int base = t * CH;
    int loc[CH];
    int s = 0;
    #pragma unroll
    for (int i = 0; i < CH; ++i) {
        int idx = base + i;
        int v = (idx < NSEQ) ? hist[idx] : 0;
        loc[i] = s; s += v;
    }
    const int lane = t & 63, w = t >> 6;
    int incl = s;
    #pragma unroll
    for (int off = 1; off < 64; off <<= 1) {
        int n = __shfl_up(incl, off);
        if (lane >= off) incl += n;
    }
    __shared__ int wsum[16];
    if (lane == 63) wsum[w] = incl;
    __syncthreads();
    if (t == 0) {
        int acc = 0;
        #pragma unroll
        for (int k = 0; k < 16; ++k) { int v = wsum[k]; wsum[k] = acc; acc += v; }
    }
    __syncthreads();
    const int excl = incl - s + wsum[w];
    #pragma unroll
    for (int i = 0; i < CH; ++i) {
        int idx = base + i;
        if (idx < NSEQ) {
            int e = excl + loc[i];
            hist[idx] = e;
            hstart[idx] = e;
        }
    }
    if (t == 0) hstart[NSEQ] = NBS;
}

__global__ __launch_bounds__(256) void scatter_kernel(const int* __restrict__ seq,
                                                      int* __restrict__ hist,
                                                      int* __restrict__ perm) {
    int i = blockIdx.x * 256 + threadIdx.x;
    if (i < NBS) {
        int pos = atomicAdd(&hist[seq[i]], 1);
        perm[pos] = i;
    }
}

// -------------------- Kernel 1: attention, all-MFMA --------------------
// one block per b, 256 threads (4 waves); ~25 KB LDS
__global__ __launch_bounds__(256, 4) void attn_kernel(
    const int* __restrict__ user,
    const int* __restrict__ neighbor,
    const float* __restrict__ uet,
    const float* __restrict__ wq, const float* __restrict__ bq,
    const float* __restrict__ wk, const float* __restrict__ bk,
    const float* __restrict__ bv, const float* __restrict__ bo,
    const unsigned short* __restrict__ wvT, const unsigned short* __restrict__ woT,
    float* __restrict__ ws_ne2)
{
    __shared__ unsigned short kA[64*LDK];     // ne (bf16) -> ctx (bf16)
    __shared__ unsigned short qkvT[16][EE];   // B for logits MFMA: [h][e], rows 8..15 zero
    __shared__ float ue[EE];
    __shared__ float qs[EE];
    __shared__ float qkb[HH];
    __shared__ float attn_s[HH][64];
    __shared__ float maskadd[64];

    const int b = blockIdx.x;
    const int t = threadIdx.x;

    // ---- gathers: ue (f32), ne -> bf16 LDS, mask ----
    if (t < EE) ue[t] = uet[(size_t)user[b]*EE + t];
    if (t < 64) maskadd[t] = (t < SS && neighbor[b*SS + t] > 0) ? 0.f : -1e9f;
    for (int idx = t; idx < SS*32; idx += 256) {
        int s = idx >> 5, g = idx & 31;
        float4 v = ((const float4*)(uet + (size_t)neighbor[b*SS + s]*EE))[g];
        us4 o; o.x = f2bf(v.x); o.y = f2bf(v.y); o.z = f2bf(v.z); o.w = f2bf(v.w);
        *(us4*)&kA[s*LDK + g*4] = o;
    }
    for (int idx = t; idx < 14*LDK; idx += 256) kA[50*LDK + idx] = 0;
    for (int idx = t; idx < 8*EE; idx += 256) qkvT[8 + (idx >> 7)][idx & 127] = 0;
    __syncthreads();

    // ---- q = ue @ wq + bq ----
    if (t < EE) {
        float acc = bq[t];
        #pragma unroll 4
        for (int e = 0; e < EE; ++e) acc = fmaf(ue[e], wq[e*EE + t], acc);
        qs[t] = acc;
    }
    __syncthreads();

    // ---- qkvT[h][e] = Wk block-diag trick ; qkb[h] = q_h . bk_h ----
    {
        const int e = t >> 1, h0 = (t & 1) * 4;
        const float* wrow = wk + e*EE;
        #pragma unroll
        for (int j = 0; j < 4; ++j) {
            int h = h0 + j;
            float acc = 0.f;
            #pragma unroll
            for (int d = 0; d < 16; ++d) acc = fmaf(qs[h*16 + d], wrow[h*16 + d], acc);
            qkvT[h][e] = f2bf(acc);
        }
    }
    if (t < HH) {
        float acc = 0.f;
        #pragma unroll
        for (int d = 0; d < 16; ++d) acc = fmaf(qs[t*16 + d], bk[t*16 + d], acc);
        qkb[t] = acc;
    }
    __syncthreads();

    const int w    = t >> 6;       // wave -> row tile [16w, 16w+16)
    const int l    = t & 63;
    const int lrow = l & 15;
    const int kg   = l >> 4;       // 0..3

    // ---- A fragments (rows of ne, bf16) ----
    bf16x8 a0 = *(const bf16x8*)&kA[(w*16 + lrow)*LDK +  0 + kg*8];
    bf16x8 a1 = *(const bf16x8*)&kA[(w*16 + lrow)*LDK + 32 + kg*8];
    bf16x8 a2 = *(const bf16x8*)&kA[(w*16 + lrow)*LDK + 64 + kg*8];
    bf16x8 a3 = *(const bf16x8*)&kA[(w*16 + lrow)*LDK + 96 + kg*8];

    // ---- logits = ne @ qkvT^T via MFMA (covers ALL 64 rows) ----
    {
        bf16x8 b0 = *(const bf16x8*)&qkvT[lrow][ 0 + kg*8];
        bf16x8 b1 = *(const bf16x8*)&qkvT[lrow][32 + kg*8];
        bf16x8 b2 = *(const bf16x8*)&qkvT[lrow][64 + kg*8];
        bf16x8 b3 = *(const bf16x8*)&qkvT[lrow][96 + kg*8];
        f32x4 c = {0.f, 0.f, 0.f, 0.f};
        c = __builtin_amdgcn_mfma_f32_16x16x32_bf16(a0, b0, c, 0, 0, 0);
        c = __builtin_amdgcn_mfma_f32_16x16x32_bf16(a1, b1, c, 0, 0, 0);
        c = __builtin_amdgcn_mfma_f32_16x16x32_bf16(a2, b2, c, 0, 0, 0);
        c = __builtin_amdgcn_mfma_f32_16x16x32_bf16(a3, b3, c, 0, 0, 0);
        const int h = lrow;            // col = lane&15
        if (h < HH) {
            #pragma unroll
            for (int rg = 0; rg < 4; ++rg) {
                const int row = w*16 + kg*4 + rg;
                attn_s[h][row] = (c[rg] + qkb[h]) * 0.25f + maskadd[row];
            }
        }
    }
    __syncthreads();

    // ---- softmax over s per head (one wave) ----
    if (t < 64) {
        int h = t >> 3, ll = t & 7;
        float mx = -3e38f;
        #pragma unroll
        for (int i = 0; i < 7; ++i) { int s = i*8 + ll; if (s < SS) mx = fmaxf(mx, attn_s[h][s]); }
        mx = fmaxf(mx, __shfl_xor(mx, 1));
        mx = fmaxf(mx, __shfl_xor(mx, 2));
        mx = fmaxf(mx, __shfl_xor(mx, 4));
        float ev[7]; float sm_ = 0.f;
        #pragma unroll
        for (int i = 0; i < 7; ++i) {
            int s = i*8 + ll; ev[i] = 0.f;
            if (s < SS) { ev[i] = expf(attn_s[h][s] - mx); sm_ += ev[i]; }
        }
        sm_ += __shfl_xor(sm_, 1);
        sm_ += __shfl_xor(sm_, 2);
        sm_ += __shfl_xor(sm_, 4);
        float inv = 1.f / sm_;
        #pragma unroll
        for (int i = 0; i < 7; ++i) { int s = i*8 + ll; if (s < SS) attn_s[h][s] = ev[i] * inv; }
    }
    __syncthreads();

    // ---- MFMA GEMM1: v = ne @ wv ; ctx = (v + bv) * attn -> bf16 into kA ----
    f32x4 acc[8];
    #pragma unroll
    for (int nt = 0; nt < 8; ++nt) {
        const unsigned short* bp = wvT + (nt*16 + lrow)*EE + kg*8;
        bf16x8 b0 = *(const bf16x8*)&bp[0];
        bf16x8 b1 = *(const bf16x8*)&bp[32];
        bf16x8 b2 = *(const bf16x8*)&bp[64];
        bf16x8 b3 = *(const bf16x8*)&bp[96];
        f32x4 c = {0.f, 0.f, 0.f, 0.f};
        c = __builtin_amdgcn_mfma_f32_16x16x32_bf16(a0, b0, c, 0, 0, 0);
        c = __builtin_amdgcn_mfma_f32_16x16x32_bf16(a1, b1, c, 0, 0, 0);
        c = __builtin_amdgcn_mfma_f32_16x16x32_bf16(a2, b2, c, 0, 0, 0);
        c = __builtin_amdgcn_mfma_f32_16x16x32_bf16(a3, b3, c, 0, 0, 0);
        acc[nt] = c;
    }
    #pragma unroll
    for (int nt = 0; nt < 8; ++nt) {
        const int col = nt*16 + lrow;
        const float bvc = bv[col];
        #pragma unroll
        for (int rg = 0; rg < 4; ++rg) {
            const int row = w*16 + kg*4 + rg;
            const float av = (row < SS) ? attn_s[nt][row] : 0.f;
            kA[row*LDK + col] = f2bf((acc[nt][rg] + bvc) * av);
        }
    }
    __syncthreads();

    // ---- MFMA GEMM2: ne2 = ctx @ wo + bo -> global ----
    bf16x8 c0 = *(const bf16x8*)&kA[(w*16 + lrow)*LDK +  0 + kg*8];
    bf16x8 c1 = *(const bf16x8*)&kA[(w*16 + lrow)*LDK + 32 + kg*8];
    bf16x8 c2 = *(const bf16x8*)&kA[(w*16 + lrow)*LDK + 64 + kg*8];
    bf16x8 c3 = *(const bf16x8*)&kA[(w*16 + lrow)*LDK + 96 + kg*8];

    #pragma unroll
    for (int nt = 0; nt < 8; ++nt) {
        const unsigned short* bp = woT + (nt*16 + lrow)*EE + kg*8;
        bf16x8 b0 = *(const bf16x8*)&bp[0];
        bf16x8 b1 = *(const bf16x8*)&bp[32];
        bf16x8 b2 = *(const bf16x8*)&bp[64];
        bf16x8 b3 = *(const bf16x8*)&bp[96];
        f32x4 c = {0.f, 0.f, 0.f, 0.f};
        c = __builtin_amdgcn_mfma_f32_16x16x32_bf16(c0, b0, c, 0, 0, 0);
        c = __builtin_amdgcn_mfma_f32_16x16x32_bf16(c1, b1, c, 0, 0, 0);
        c = __builtin_amdgcn_mfma_f32_16x16x32_bf16(c2, b2, c, 0, 0, 0);
        c = __builtin_amdgcn_mfma_f32_16x16x32_bf16(c3, b3, c, 0, 0, 0);
        const int col = nt*16 + lrow;
        const float boc = bo[col];
        #pragma unroll
        for (int rg = 0; rg < 4; ++rg) {
            const int row = w*16 + kg*4 + rg;
            if (row < SS)
                ws_ne2[((size_t)b*SS + row)*EE + col] = c[rg] + boc;
        }
    }
}

// -------------------- Kernel 2: per-unique-j region, barrier-free --------------------
// one block per j; K rows nontemporal into registers; waves own disjoint r-rows
__global__ __launch_bounds__(256, 6) void region_kernel(
    const int* __restrict__ neighbor, const int* __restrict__ item,
    const float* __restrict__ ui_lcu, const float* __restrict__ iu_lcu,
    const float* __restrict__ iet, const float* __restrict__ ws_ne2,
    const int* __restrict__ hstart, const int* __restrict__ perm,
    float* __restrict__ ws_rating)
{
    const int j = blockIdx.x;
    const int start = hstart[j];
    const int end   = hstart[j + 1];
    if (start >= end) return;

    const int t = threadIdx.x;
    const int r = t >> 3, l = t & 7;

    const f32x4* kiu_g = (const f32x4*)(iu_lcu + ((size_t)j*RR + r)*EE);
    const f32x4* kui_g = (const f32x4*)(ui_lcu + ((size_t)j*RR + r)*EE);
    f32x4 kiu_r[4], kui_r[4];
    #pragma unroll
    for (int i = 0; i < 4; ++i) {
        kiu_r[i] = __builtin_nontemporal_load(&kiu_g[l + 8*i]);
        kui_r[i] = __builtin_nontemporal_load(&kui_g[l + 8*i]);
    }

    for (int o = start; o < end; ++o) {
        const int bs = perm[o];
        const int b  = bs / SS;
        const float4* n4 = (const float4*)(ws_ne2 + (size_t)bs*EE);
        const float4* i4 = (const float4*)(iet + (size_t)item[b]*EE);

        float np_ = 0.f, ip_ = 0.f;
        #pragma unroll
        for (int i = 0; i < 4; ++i) {
            int c = l + 8*i;
            np_ += dot4v(kiu_r[i], n4[c]);
            ip_ += dot4v(kui_r[i], i4[c]);
        }
        np_ += __shfl_xor(np_, 1); np_ += __shfl_xor(np_, 2); np_ += __shfl_xor(np_, 4);
        ip_ += __shfl_xor(ip_, 1); ip_ += __shfl_xor(ip_, 2); ip_ += __shfl_xor(ip_, 4);

        const float w = (neighbor[bs] > 0) ? 1.f : 0.f;
        if (l == 0) ws_rating[(size_t)bs*RR + r] = np_ * ip_ * w;
    }
}

// -------------------- Kernel 3: max over s, FC, softmax --------------------
__global__ __launch_bounds__(256) void head_kernel(
    const float* __restrict__ ws_rating,
    const float* __restrict__ fc_w, const float* __restrict__ fc_b,
    float* __restrict__ out)
{
    __shared__ float part[8][RR];
    __shared__ float urv[RR];
    __shared__ float lg[NC];
    const int b = blockIdx.x, t = threadIdx.x;
    const int r = t & 31, sub = t >> 5;

    float m = -3e38f;
    for (int s = sub; s < SS; s += 8)
        m = fmaxf(m, ws_rating[((size_t)b*SS + s)*RR + r]);
    part[sub][r] = m;
    __syncthreads();
    if (t < RR) {
        float mm = part[0][t];
        #pragma unroll
        for (int k = 1; k < 8; ++k) mm = fmaxf(mm, part[k][t]);
        urv[t] = mm;
    }
    __syncthreads();
    if (t < NC) {
        float acc = fc_b[t];
        #pragma unroll
        for (int rr = 0; rr < RR; ++rr) acc = fmaf(urv[rr], fc_w[rr*NC + t], acc);
        lg[t] = acc;
    }
    __syncthreads();
    if (t < NC) {
        float mx = lg[0];
        #pragma unroll
        for (int c = 1; c < NC; ++c) mx = fmaxf(mx, lg[c]);
        float sm = 0.f;
        #pragma unroll
        for (int c = 0; c < NC; ++c) sm += expf(lg[c] - mx);
        out[b*NC + t] = expf(lg[t] - mx) / sm;
    }
}

extern "C" void kernel_launch(void* const* d_in, const int* in_sizes, int n_in,
                              void* d_out, int out_size, void* d_ws, size_t ws_size,
                              hipStream_t stream) {
    const int*   user     = (const int*)d_in[0];
    const int*   item     = (const int*)d_in[1];
    const int*   neighbor = (const int*)d_in[2];
    const int*   seq      = (const int*)d_in[3];
    const float* uet      = (const float*)d_in[4];
    const float* iet      = (const float*)d_in[5];
    const float* ui_lcu   = (const float*)d_in[6];
    const float* iu_lcu   = (const float*)d_in[7];
    const float* wq = (const float*)d_in[8];   const float* bq = (const float*)d_in[9];
    const float* wk = (const float*)d_in[10];  const float* bk = (const float*)d_in[11];
    const float* wv = (const float*)d_in[12];  const float* bv = (const float*)d_in[13];
    const float* wo = (const float*)d_in[14];  const float* bo = (const float*)d_in[15];
    const float* fcw = (const float*)d_in[16]; const float* fcb = (const float*)d_in[17];

    float* ws = (float*)d_ws;
    float* ws_ne2    = ws;                                       // B*S*E f32
    float* ws_rating = ws_ne2 + (size_t)BB*SS*EE;                // B*S*R f32
    unsigned short* wvT = (unsigned short*)(ws_rating + (size_t)BB*SS*RR);  // 128*128 bf16
    unsigned short* woT = wvT + EE*EE;                           // 128*128 bf16
    int*   hist      = (int*)(woT + EE*EE);                      // NSEQ
    int*   hstart    = hist + NSEQ;                              // NSEQ+1
    int*   perm      = hstart + NSEQ + 1;                        // NBS
    float* out = (float*)d_out;

    // ---- prep: weight transpose/convert + counting sort ----
    hipLaunchKernelGGL(conv_kernel, dim3(256), dim3(128), 0, stream, wv, wo, wvT, woT);
    hipMemsetAsync(hist, 0, NSEQ * sizeof(int), stream);
    hipLaunchKernelGGL(hist_kernel, dim3((NBS + 255)/256), dim3(256), 0, stream, seq, hist);
    hipLaunchKernelGGL(scan_kernel, dim3(1), dim3(1024), 0, stream, hist, hstart);
    hipLaunchKernelGGL(scatter_kernel, dim3((NBS + 255)/256), dim3(256), 0, stream, seq, hist, perm);

    // ---- attention (all-MFMA) ----
    hipLaunchKernelGGL(attn_kernel, dim3(BB), dim3(256), 0, stream,
                       user, neighbor, uet,
                       wq, bq, wk, bk, bv, bo, wvT, woT, ws_ne2);

    // ---- region: one block per unique seq value, barrier-free ----
    hipLaunchKernelGGL(region_kernel, dim3(NSEQ), dim3(256), 0, stream,
                       neighbor, item, ui_lcu, iu_lcu, iet, ws_ne2, hstart, perm, ws_rating);

    hipLaunchKernelGGL(head_kernel, dim3(BB), dim3(256), 0, stream,
                       ws_rating, fcw, fcb, out);
}